// Round 9
// baseline (129.349 us; speedup 1.0000x reference)
//
#include <hip/hip_runtime.h>

typedef __attribute__((ext_vector_type(4))) float          f32x4;
typedef __attribute__((ext_vector_type(8))) short          bf16x8;
typedef __attribute__((ext_vector_type(4))) unsigned short u16x4;
typedef __attribute__((ext_vector_type(8))) unsigned short u16x8;

__device__ __forceinline__ unsigned short f2bf(float f) {
  union { float f; unsigned u; } v; v.f = f;
  unsigned r = v.u + 0x7fffu + ((v.u >> 16) & 1u);   // RNE
  return (unsigned short)(r >> 16);
}

__device__ __forceinline__ void gload_lds16(const void* g, void* l) {
  __builtin_amdgcn_global_load_lds(
      (const __attribute__((address_space(1))) unsigned int*)g,
      (__attribute__((address_space(3))) unsigned int*)l, 16, 0, 0);
}

#define S_  128
#define I_  256
#define D_  64
#define P_  32
#define DO_ 128

// ---------------------------------------------------------------------------
// K1: LayerNorm + projections (grid 1024 = i x 4 s-chunks) + folded Wo pack.
//   LtT[i*32+p][s], RtT[j*32+q][s]  (8192 x 128 bf16, 256 B rows)
//   WoP[o][k'] with k' = q*32+p holding Wo[o][p*32+q]  (128 x 1024 bf16)
// ---------------------------------------------------------------------------
__global__ __launch_bounds__(256) void ln_proj(
    const float* __restrict__ M,  const float* __restrict__ gamma,
    const float* __restrict__ beta,
    const float* __restrict__ Wa, const float* __restrict__ ba,
    const float* __restrict__ Wb, const float* __restrict__ bb,
    const float* __restrict__ Wo,
    unsigned short* __restrict__ LtT, unsigned short* __restrict__ RtT,
    unsigned short* __restrict__ WoP)
{
  __shared__ __align__(16) float mnAll[32 * 68];
  __shared__ __align__(16) float lsm[32 * 33];
  __shared__ __align__(16) float rsm[32 * 33];

  const int tid  = threadIdx.x;
  const int lane = tid & 63;
  const int w    = tid >> 6;
  const int i    = blockIdx.x >> 2;
  const int sq   = blockIdx.x & 3;

  const float g  = gamma[lane];
  const float be = beta[lane];
  #pragma unroll
  for (int u = 0; u < 8; ++u) {
    int s_loc = w * 8 + u;
    int s     = sq * 32 + s_loc;
    float x = M[(s * I_ + i) * D_ + lane];
    float s1 = x, s2 = x * x;
    #pragma unroll
    for (int m = 1; m < 64; m <<= 1) {
      s1 += __shfl_xor(s1, m, 64);
      s2 += __shfl_xor(s2, m, 64);
    }
    float mean = s1 * (1.0f / 64.0f);
    float var  = s2 * (1.0f / 64.0f) - mean * mean;
    mnAll[s_loc * 68 + lane] = (x - mean) * rsqrtf(var + 1e-5f) * g + be;
  }
  __syncthreads();

  {
    const int p    = lane & 31;
    const int side = lane >> 5;
    const float* wrow = (side ? Wb : Wa) + p * D_;
    const float  bias = side ? bb[p] : ba[p];
    f32x4 wv[16];
    #pragma unroll
    for (int c = 0; c < 16; ++c) wv[c] = *(const f32x4*)(wrow + c * 4);
    float* dst = side ? rsm : lsm;
    #pragma unroll
    for (int u = 0; u < 8; ++u) {
      int s_loc = w * 8 + u;
      float acc = bias;
      #pragma unroll
      for (int c = 0; c < 16; ++c) {
        f32x4 m4 = *(const f32x4*)(&mnAll[s_loc * 68 + c * 4]);
        acc += m4.x * wv[c].x + m4.y * wv[c].y + m4.z * wv[c].z + m4.w * wv[c].w;
      }
      dst[s_loc * 33 + p] = acc;
    }
  }
  __syncthreads();

  {
    int arr = tid >> 7;
    int p   = (tid >> 2) & 31;
    int c   = tid & 3;
    int s0  = c * 8;
    const float* src = arr ? rsm : lsm;
    unsigned short* dstg = (arr ? RtT : LtT) + (i * 32 + p) * S_ + sq * 32 + s0;
    u16x8 v;
    #pragma unroll
    for (int k = 0; k < 8; ++k) v[k] = f2bf(src[(s0 + k) * 33 + p]);
    *(u16x8*)dstg = v;
  }

  if (blockIdx.x < 512) {
    int f = (int)blockIdx.x * 256 + tid;
    int o = f >> 10, kp = f & 1023, q = kp >> 5, p = kp & 31;
    WoP[f] = f2bf(Wo[o * 1024 + p * 32 + q]);
  }
}

// ---------------------------------------------------------------------------
// K2: fused GEMM. Grid 512 (= bi 32 x bj 16), 512 thr (8 waves), 2 blocks/CU.
// Block: 8 i-residues x 16 j-residues. A-fragments (Lt) read DIRECTLY from
// global (L2) into registers once. Per k'-chunk c (4 q values):
//   GEMM1 (af x RtS_c) -> Osh_c -> GEMM2 (Osh_c x WoS_c) -> zacc.
// LDS: RtS 16K | WoS 32K | Osh 32K = 80 KB -> 2 blocks/CU.
// Staged tiles are [rows][128 bf16] with byte swizzle col ^= (row&7)<<4
// folded into the global source address (linear LDS dest, rule both-sides).
// ---------------------------------------------------------------------------
__global__ __launch_bounds__(512, 4) void fused_gemm(
    const unsigned short* __restrict__ LtT,
    const unsigned short* __restrict__ RtT,
    const unsigned short* __restrict__ WoP,
    const float* __restrict__ bo,
    float* __restrict__ Z)
{
  __shared__ __align__(16) unsigned short ldsmem[40960];   // 81920 B
  char* Lc  = (char*)ldsmem;
  char* RtS = Lc;            // 16384 B : 64 rows  (16 j x 4 q) x 256 B
  char* WoS = Lc + 16384;    // 32768 B : 128 rows (o) x 256 B
  char* Osh = Lc + 49152;    // 32768 B : 128 rows (pair) x 256 B

  const int tid  = threadIdx.x;
  const int lane = tid & 63;
  const int wid  = tid >> 6;
  const int l15  = lane & 15;
  const int l4   = lane >> 4;

  const int bid = ((int)blockIdx.x & 7) * 64 + ((int)blockIdx.x >> 3); // XCD swz
  const int bi  = bid >> 4;    // 0..31 (8 i each)
  const int bj  = bid & 15;    // 0..15 (16 j each)

  // ---- stage RtS chunk 0 + WoS chunk 0 ----
  #pragma unroll
  for (int t2 = 0; t2 < 2; ++t2) {
    int t = wid + t2 * 8;
    unsigned off = (unsigned)t * 1024u;
    unsigned y = off + (unsigned)lane * 16u;
    unsigned lr = y >> 8, cb = y & 255u;
    unsigned grow = (unsigned)bj * 512u + (lr >> 2) * 32u + (lr & 3u);
    gload_lds16((const char*)RtT + grow * 256u + (cb ^ ((lr & 7u) << 4)), RtS + off);
  }
  #pragma unroll
  for (int t2 = 0; t2 < 4; ++t2) {
    int t = wid + t2 * 8;
    unsigned off = (unsigned)t * 1024u;
    unsigned y = off + (unsigned)lane * 16u;
    unsigned o = y >> 8, cb = y & 255u;
    gload_lds16((const char*)WoP + o * 2048u + (cb ^ ((o & 7u) << 4)), WoS + off);
  }

  // ---- A-fragments from global (L2-resident, per-lane b128 loads) ----
  bf16x8 af[4][2];
  #pragma unroll
  for (int kk = 0; kk < 4; ++kk)
    #pragma unroll
    for (int ai = 0; ai < 2; ++ai) {
      unsigned rg = (unsigned)(bi * 256 + (wid * 2 + ai) * 16 + l15);
      af[kk][ai] = *(const bf16x8*)(LtT + rg * 128u + (unsigned)(kk * 32 + l4 * 8));
    }

  const int wm = wid >> 2;   // GEMM2 pair-quadrant base (4 Mtiles each)
  const int wn = wid & 3;    // GEMM2 o-quadrant (2 Ntiles each)

  float bov[2];
  #pragma unroll
  for (int n_i = 0; n_i < 2; ++n_i) bov[n_i] = bo[(wn * 2 + n_i) * 16 + l15];

  f32x4 zacc[4][2];
  #pragma unroll
  for (int a = 0; a < 4; ++a)
    #pragma unroll
    for (int b = 0; b < 2; ++b) { f32x4 zz = {0.f,0.f,0.f,0.f}; zacc[a][b] = zz; }

  __syncthreads();   // staged chunk-0 data visible

  for (int c = 0; c < 8; ++c) {
    // ---------------- GEMM1_c : 256 ip x 64 n (16j x 4q), K=128 ----------
    // two bt-halves to bound register pressure (acc[2][2] each)
    #pragma unroll
    for (int bh = 0; bh < 2; ++bh) {
      f32x4 acc[2][2];
      #pragma unroll
      for (int a = 0; a < 2; ++a)
        #pragma unroll
        for (int b = 0; b < 2; ++b) { f32x4 zz = {0.f,0.f,0.f,0.f}; acc[a][b] = zz; }

      #pragma unroll
      for (int kk = 0; kk < 4; ++kk) {
        bf16x8 bfr[2];
        #pragma unroll
        for (int b2 = 0; b2 < 2; ++b2) {
          unsigned r = (unsigned)((bh * 2 + b2) * 16 + l15);
          bfr[b2] = *(const bf16x8*)(RtS + r * 256u +
                      (((unsigned)(kk * 64 + l4 * 16)) ^ ((r & 7u) << 4)));
        }
        #pragma unroll
        for (int ai = 0; ai < 2; ++ai)
          #pragma unroll
          for (int b2 = 0; b2 < 2; ++b2)
            acc[ai][b2] = __builtin_amdgcn_mfma_f32_16x16x32_bf16(
                af[kk][ai], bfr[b2], acc[ai][b2], 0, 0, 0);
      }

      // O -> Osh. D-layout: col n = l15, row ip = l4*4 + r.
      #pragma unroll
      for (int ai = 0; ai < 2; ++ai) {
        int at = wid * 2 + ai;
        unsigned ihi = (unsigned)(at >> 1) * 16u;            // i_loc*16
        unsigned p0  = (unsigned)((at & 1) * 16 + l4 * 4);   // p base (mult 4)
        #pragma unroll
        for (int b2 = 0; b2 < 2; ++b2) {
          unsigned n = (unsigned)((bh * 2 + b2) * 16 + l15); // local n
          unsigned pair = ihi + (n >> 2);                    // i_loc*16 + j
          unsigned cb   = (n & 3u) * 64u + p0 * 2u;          // (q_sub*32+p)*2
          u16x4 v;
          v.x = f2bf(acc[ai][b2][0]);
          v.y = f2bf(acc[ai][b2][1]);
          v.z = f2bf(acc[ai][b2][2]);
          v.w = f2bf(acc[ai][b2][3]);
          *(u16x4*)(Osh + pair * 256u + (cb ^ ((pair & 7u) << 4))) = v;
        }
      }
    }

    __syncthreads();   // B2: Osh visible; RtS_c consumed

    // stage RtS chunk c+1 (overlaps GEMM2; drains at B3)
    if (c < 7) {
      #pragma unroll
      for (int t2 = 0; t2 < 2; ++t2) {
        int t = wid + t2 * 8;
        unsigned off = (unsigned)t * 1024u;
        unsigned y = off + (unsigned)lane * 16u;
        unsigned lr = y >> 8, cb = y & 255u;
        unsigned grow = (unsigned)bj * 512u + (lr >> 2) * 32u +
                        (unsigned)(c + 1) * 4u + (lr & 3u);
        gload_lds16((const char*)RtT + grow * 256u + (cb ^ ((lr & 7u) << 4)),
                    RtS + off);
      }
    }

    // ---------------- GEMM2_c : 128 pairs x 128 o, K=128 ------------------
    #pragma unroll
    for (int kk2 = 0; kk2 < 4; ++kk2) {
      bf16x8 afr[4], wbr[2];
      #pragma unroll
      for (int m_i = 0; m_i < 4; ++m_i) {
        unsigned r = (unsigned)((wm * 4 + m_i) * 16 + l15);
        afr[m_i] = *(const bf16x8*)(Osh + r * 256u +
                     (((unsigned)(kk2 * 64 + l4 * 16)) ^ ((r & 7u) << 4)));
      }
      #pragma unroll
      for (int n_i = 0; n_i < 2; ++n_i) {
        unsigned r = (unsigned)((wn * 2 + n_i) * 16 + l15);
        wbr[n_i] = *(const bf16x8*)(WoS + r * 256u +
                     (((unsigned)(kk2 * 64 + l4 * 16)) ^ ((r & 7u) << 4)));
      }
      #pragma unroll
      for (int m_i = 0; m_i < 4; ++m_i)
        #pragma unroll
        for (int n_i = 0; n_i < 2; ++n_i)
          zacc[m_i][n_i] = __builtin_amdgcn_mfma_f32_16x16x32_bf16(
              afr[m_i], wbr[n_i], zacc[m_i][n_i], 0, 0, 0);
    }

    __syncthreads();   // B3: WoS_c consumed; RtS_{c+1} staged

    // stage WoS chunk c+1 (overlaps next GEMM1; drains at next B2)
    if (c < 7) {
      #pragma unroll
      for (int t2 = 0; t2 < 4; ++t2) {
        int t = wid + t2 * 8;
        unsigned off = (unsigned)t * 1024u;
        unsigned y = off + (unsigned)lane * 16u;
        unsigned o = y >> 8, cb = y & 255u;
        gload_lds16((const char*)WoP + o * 2048u + (unsigned)(c + 1) * 256u +
                    (cb ^ ((o & 7u) << 4)), WoS + off);
      }
    }
  }

  // ---- write Z ----
  #pragma unroll
  for (int m_i = 0; m_i < 4; ++m_i)
    #pragma unroll
    for (int r = 0; r < 4; ++r) {
      int pair = (wm * 4 + m_i) * 16 + l4 * 4 + r;
      int i_loc = pair >> 4, j_loc = pair & 15;
      float* zrow = Z + (((bi * 8 + i_loc) * I_) + (bj * 16 + j_loc)) * DO_;
      #pragma unroll
      for (int n_i = 0; n_i < 2; ++n_i)
        zrow[(wn * 2 + n_i) * 16 + l15] = zacc[m_i][n_i][r] + bov[n_i];
    }
}

// ---------------------------------------------------------------------------
extern "C" void kernel_launch(void* const* d_in, const int* in_sizes, int n_in,
                              void* d_out, int out_size, void* d_ws, size_t ws_size,
                              hipStream_t stream) {
  const float* M     = (const float*)d_in[0];
  const float* gamma = (const float*)d_in[1];
  const float* beta  = (const float*)d_in[2];
  const float* Wa    = (const float*)d_in[3];
  const float* ba    = (const float*)d_in[4];
  const float* Wb    = (const float*)d_in[5];
  const float* bb    = (const float*)d_in[6];
  const float* Wo    = (const float*)d_in[7];
  const float* bo    = (const float*)d_in[8];
  float* Z = (float*)d_out;

  unsigned short* LtT = (unsigned short*)d_ws;
  unsigned short* RtT = LtT + 1048576;
  unsigned short* WoP = RtT + 1048576;

  ln_proj<<<1024, 256, 0, stream>>>(M, gamma, beta, Wa, ba, Wb, bb, Wo,
                                    LtT, RtT, WoP);
  fused_gemm<<<512, 512, 0, stream>>>(LtT, RtT, WoP, bo, Z);
}